// Round 7
// baseline (572.209 us; speedup 1.0000x reference)
//
#include <hip/hip_runtime.h>

typedef unsigned short u16;
typedef unsigned int u32;
typedef short bf16x8 __attribute__((ext_vector_type(8)));
typedef float f32x4 __attribute__((ext_vector_type(4)));

// ---- bf16 helpers ----
__device__ __forceinline__ u16 f2bf(float f) {
  union { float f; u32 i; } v; v.f = f;
  u32 x = v.i;
  return (u16)((x + 0x7fffu + ((x >> 16) & 1u)) >> 16);  // RNE
}

union Pack16 { u16 h[16]; float4 f4[2]; };

// ---- direct global->LDS DMA, 16B per lane (wave-uniform LDS base) ----
__device__ __forceinline__ void gld16(const u16* g, u16* l) {
  __builtin_amdgcn_global_load_lds((const __attribute__((address_space(1))) u32*)g,
                                   (__attribute__((address_space(3))) u32*)l, 16, 0, 0);
}

// =====================================================================
// f32 -> bf16 streaming converters (z-batched pair + 5-weight batch)
// =====================================================================
struct C2 { const float* s[2]; u16* d[2]; };
__global__ __launch_bounds__(256) void conv2_kernel(C2 c) {
  const int z = blockIdx.z;
  const size_t i = (size_t)blockIdx.x * 256 + threadIdx.x;  // x8 elems
  const float4* s = (const float4*)c.s[z] + i * 2;
  float4 a = s[0], b = s[1];
  union { u16 h[8]; float4 f; } o;
  o.h[0] = f2bf(a.x); o.h[1] = f2bf(a.y); o.h[2] = f2bf(a.z); o.h[3] = f2bf(a.w);
  o.h[4] = f2bf(b.x); o.h[5] = f2bf(b.y); o.h[6] = f2bf(b.z); o.h[7] = f2bf(b.w);
  *(float4*)(c.d[z] + i * 8) = o.f;
}

struct W5 { const float* p[5]; };
__global__ __launch_bounds__(256) void conv_w_kernel(W5 w, u16* __restrict__ dst) {
  const int m = blockIdx.x >> 9;                                    // matrix idx
  const size_t i = (size_t)(blockIdx.x & 511) * 256 + threadIdx.x;  // x8 elems
  const float4* s = (const float4*)w.p[m] + i * 2;
  float4 a = s[0], b = s[1];
  union { u16 h[8]; float4 f; } o;
  o.h[0] = f2bf(a.x); o.h[1] = f2bf(a.y); o.h[2] = f2bf(a.z); o.h[3] = f2bf(a.w);
  o.h[4] = f2bf(b.x); o.h[5] = f2bf(b.y); o.h[6] = f2bf(b.z); o.h[7] = f2bf(b.w);
  *(float4*)(dst + ((size_t)m << 20) + i * 8) = o.f;
}

// ---- per-lane global address of a 16B chunk of the A operand ----
// ASRC 0: bf16 row-major [.][1024].  ASRC 1: bf16 Q-layout [N,H,S,DK].
template<int ASRC>
__device__ __forceinline__ const u16* aAddr(const u16* A, int row, int k) {
  if constexpr (ASRC == 0) {
    return A + (size_t)row * 1024 + k;
  } else {
    const int n = row >> 10, s = row & 1023, h = k >> 6;
    return A + ((size_t)((n * 16 + h) * 1024 + s)) * 64 + (k & 63);  // 16B chunk stays in one h
  }
}

// =====================================================================
// z-BATCHED GEMM, 2-PHASE DOUBLE-BUFFERED (T3-minimum recipe):
//   prologue: STAGE(buf0, t=0)
//   iter t:   __syncthreads()            // drains loads issued LAST iter
//             STAGE(buf[t+1&1], t+1)     // loads fly across compute+next bar
//             ds_read(buf[t&1]) + MFMA
// One barrier per K-step; load latency hidden under a full compute phase.
// MODE 0: out bf16 Q-layout; MODE 1: out f32 [S,N,D]; MODE 2: V^T layout.
// =====================================================================
struct GB { const void* A[2]; const void* W[2]; const float* bias[2]; void* out[2]; };

template<int MODEA, int MODEB, int ASRC, int WBF>
__global__ __launch_bounds__(256, 2) void gemm_bt(GB gb) {
  __shared__ __align__(16) u16 At[2][128 * 32];  // 2 x 8KB, linear (gld16 dest)
  __shared__ __align__(16) u16 Bt[2][128 * 32];

  const int z = blockIdx.z;
  const u16* Ab = (const u16*)gb.A[z];
  const u16* Wb = (const u16*)gb.W[z];
  const float* bias = gb.bias[z];
  void* outv = gb.out[z];
  const int mode = z ? MODEB : MODEA;

  const int tid = threadIdx.x;
  const int lane = tid & 63, wave = tid >> 6;
  const int quad = lane >> 4, l16 = lane & 15;
  const int bm = blockIdx.y * 128, bn = blockIdx.x * 128;
  const int wm = (wave >> 1) * 64, wn = (wave & 1) * 64;

  const int r0 = wave * 32;            // wave's 32-row slice (2 instrs per tile)
  const int lrow = lane >> 2;          // 0..15 (implicit in gld16 lane offset)
  const int lk = (lane & 3) * 8;       // 0,8,16,24 (bf16 elems)
  (void)lrow;

  const int srow = tid >> 1, scol = (tid & 1) * 16;  // W f32 fallback coords

  f32x4 acc[4][4];
#pragma unroll
  for (int i = 0; i < 4; i++)
#pragma unroll
    for (int j = 0; j < 4; j++) acc[i][j] = (f32x4){0.f, 0.f, 0.f, 0.f};

  float4 wf[4];  // f32-W fallback regs (held one step ahead)

  auto loadWf = [&](int k0) {
    const float* wp = (const float*)Wb + (size_t)(bn + srow) * 1024 + k0 + scol;
#pragma unroll
    for (int q = 0; q < 4; q++) wf[q] = ((const float4*)wp)[q];
  };
  auto stageA = [&](int b, int k0) {
    const int row = bm + r0 + (lane >> 2);
    gld16(aAddr<ASRC>(Ab, row, k0 + lk), At[b] + r0 * 32);
    gld16(aAddr<ASRC>(Ab, row + 16, k0 + lk), At[b] + (r0 + 16) * 32);
  };
  auto stageW = [&](int b, int k0) {
    if constexpr (WBF) {
      const int row = bn + r0 + (lane >> 2);
      gld16(Wb + (size_t)row * 1024 + k0 + lk, Bt[b] + r0 * 32);
      gld16(Wb + (size_t)(row + 16) * 1024 + k0 + lk, Bt[b] + (r0 + 16) * 32);
    } else {  // convert regs held in wf (loaded for this k0 earlier)
      Pack16 pb;
#pragma unroll
      for (int q = 0; q < 4; q++) {
        pb.h[q * 4 + 0] = f2bf(wf[q].x);
        pb.h[q * 4 + 1] = f2bf(wf[q].y);
        pb.h[q * 4 + 2] = f2bf(wf[q].z);
        pb.h[q * 4 + 3] = f2bf(wf[q].w);
      }
      *(float4*)(Bt[b] + srow * 32 + scol) = pb.f4[0];
      *(float4*)(Bt[b] + srow * 32 + scol + 8) = pb.f4[1];
    }
  };

  // ---- prologue: stage tile 0 into buf 0 ----
  if constexpr (!WBF) loadWf(0);
  stageA(0, 0);
  stageW(0, 0);
  if constexpr (!WBF) loadWf(32);  // regs now hold k=32 data

  for (int t = 0; t < 32; ++t) {
    const int cb = t & 1, nb = cb ^ 1;
    __syncthreads();  // drains loads issued one full iteration ago; buf[cb] ready, buf[nb] free
    if (t + 1 < 32) {
      stageA(nb, (t + 1) * 32);
      stageW(nb, (t + 1) * 32);            // WBF: gld16 | !WBF: convert wf(k=t+1)
      if constexpr (!WBF) if (t + 2 < 32) loadWf((t + 2) * 32);
    }

    bf16x8 af[4], bfr[4];
#pragma unroll
    for (int mt = 0; mt < 4; mt++)
      af[mt] = *(const bf16x8*)(At[cb] + (wm + mt * 16 + l16) * 32 + quad * 8);
#pragma unroll
    for (int nt = 0; nt < 4; nt++)
      bfr[nt] = *(const bf16x8*)(Bt[cb] + (wn + nt * 16 + l16) * 32 + quad * 8);
#pragma unroll
    for (int mt = 0; mt < 4; mt++)
#pragma unroll
      for (int nt = 0; nt < 4; nt++)
        acc[mt][nt] = __builtin_amdgcn_mfma_f32_16x16x32_bf16(af[mt], bfr[nt], acc[mt][nt], 0, 0, 0);
  }

#pragma unroll
  for (int mt = 0; mt < 4; mt++) {
#pragma unroll
    for (int nt = 0; nt < 4; nt++) {
      const int col = bn + wn + nt * 16 + l16;
      const float bv = bias[col];
#pragma unroll
      for (int i = 0; i < 4; i++) {
        const int row = bm + wm + mt * 16 + quad * 4 + i;
        const float v = acc[mt][nt][i] + bv;
        if (mode == 0) {
          const int s = row >> 3, n = row & 7;
          const int h = col >> 6, dk = col & 63;
          ((u16*)outv)[(size_t)(((n * 16 + h) * 1024 + s) * 64 + dk)] = f2bf(v);
        } else if (mode == 1) {
          const int n = row >> 10, s = row & 1023;
          ((float*)outv)[(size_t)((s * 8 + n) * 1024 + col)] = v;  // f32 output!
        } else {  // MODE 2: V^T head layout [N,H,DK,S]
          const int s = row >> 3, n = row & 7;
          const int h = col >> 6, dk = col & 63;
          ((u16*)outv)[(size_t)(((n * 16 + h) * 64 + dk) * 1024 + s)] = f2bf(v);
        }
      }
    }
  }
}

// =====================================================================
// FUSED dual-stream flash attention; K/V/mask register prefetch one
// tile ahead (loads issued after the staging barrier, consumed next
// iteration -> latency hidden under QK^T+softmax+PV).
// =====================================================================
__global__ __launch_bounds__(256, 2) void attn2_kernel(const u16* __restrict__ Qs_g,
                                                       const u16* __restrict__ Qp_g,
                                                       const u16* __restrict__ K,
                                                       const u16* __restrict__ Vt_g,
                                                       const int* __restrict__ mask,
                                                       u16* __restrict__ OUTs,
                                                       u16* __restrict__ OUTp) {
  __shared__ __align__(16) u16 Ks[64 * 72];      // [key][dk], stride 72
  __shared__ __align__(16) u16 Vt[64 * 64];      // [dk][key], XOR-swizzled 8-key blocks
  __shared__ __align__(16) u16 PsS[4 * 16 * 72]; // per-wave P tile, svi
  __shared__ __align__(16) u16 PsP[4 * 16 * 72]; // per-wave P tile, poi
  __shared__ float mbias[64];

  const int tid = threadIdx.x;
  const int lane = tid & 63, wave = tid >> 6;
  const int quad = lane >> 4, l16 = lane & 15;
  const int qt = blockIdx.x, nh = blockIdx.y;
  const int n = nh >> 4;
  const size_t base = (size_t)nh << 16;  // nh * 1024*64

  const int q0 = qt * 64 + wave * 16;
  bf16x8 qS0, qS1, qP0, qP1;
  {
    const u16* qp = Qs_g + base + (size_t)(q0 + l16) * 64 + quad * 8;
    qS0 = *(const bf16x8*)qp;
    qS1 = *(const bf16x8*)(qp + 32);
    const u16* qq = Qp_g + base + (size_t)(q0 + l16) * 64 + quad * 8;
    qP0 = *(const bf16x8*)qq;
    qP1 = *(const bf16x8*)(qq + 32);
  }

  float mS[4], mP[4];
  f32x4 oS[4], oP[4], lS, lP;
#pragma unroll
  for (int i = 0; i < 4; i++) { mS[i] = -1e30f; mP[i] = -1e30f; }
#pragma unroll
  for (int d = 0; d < 4; d++) { oS[d] = (f32x4){0.f, 0.f, 0.f, 0.f}; oP[d] = (f32x4){0.f, 0.f, 0.f, 0.f}; }
  lS = (f32x4){0.f, 0.f, 0.f, 0.f};
  lP = (f32x4){0.f, 0.f, 0.f, 0.f};

  // constant B-fragment: column 0 = all ones -> D[:,0] = row-sums of A
  bf16x8 vbOnes;
  {
    const short ob = (l16 == 0) ? (short)0x3F80 : (short)0;
#pragma unroll
    for (int j = 0; j < 8; j++) vbOnes[j] = ob;
  }

  const int sr = tid >> 2;           // K: key row | V^T: dk row
  const int sc = (tid & 3) * 16;     // K: dk offset | V^T: key offset
  const u16* kbase = K + base + (size_t)sr * 64 + sc;
  const u16* vbase = Vt_g + base + (size_t)sr * 1024 + sc;
  u16* vdst0 = Vt + sr * 64 + ((((sc >> 3) + 0) ^ (sr & 7)) << 3);
  u16* vdst1 = Vt + sr * 64 + ((((sc >> 3) + 1) ^ (sr & 7)) << 3);
  u16* pwS = PsS + wave * (16 * 72);
  u16* pwP = PsP + wave * (16 * 72);

  // ---- prologue: prefetch tile 0 into regs ----
  float4 kv0 = *(const float4*)(kbase);
  float4 kv1 = *(const float4*)(kbase + 8);
  float4 vv0 = *(const float4*)(vbase);
  float4 vv1 = *(const float4*)(vbase + 8);
  int mk = (tid < 64) ? mask[n * 1024 + tid] : 0;

  for (int kt = 0; kt < 16; kt++) {
    __syncthreads();  // previous iteration's LDS reads complete
    *(float4*)(Ks + sr * 72 + sc) = kv0;
    *(float4*)(Ks + sr * 72 + sc + 8) = kv1;
    *(float4*)vdst0 = vv0;
    *(float4*)vdst1 = vv1;
    if (tid < 64) mbias[tid] = mk ? -1e30f : 0.0f;
    __syncthreads();

    // ---- prefetch NEXT tile (regs free; hides under QK^T+softmax+PV) ----
    if (kt + 1 < 16) {
      kv0 = *(const float4*)(kbase + (kt + 1) * 64 * 64);
      kv1 = *(const float4*)(kbase + (kt + 1) * 64 * 64 + 8);
      vv0 = *(const float4*)(vbase + (kt + 1) * 64);
      vv1 = *(const float4*)(vbase + (kt + 1) * 64 + 8);
      mk = (tid < 64) ? mask[n * 1024 + (kt + 1) * 64 + tid] : 0;
    }

    // ---- S = Q K^T / 8 + mask, both streams (K fragments read ONCE) ----
    f32x4 sS[4], sP[4];
#pragma unroll
    for (int nt = 0; nt < 4; nt++) {
      bf16x8 b0 = *(const bf16x8*)(Ks + (nt * 16 + l16) * 72 + quad * 8);
      bf16x8 b1 = *(const bf16x8*)(Ks + (nt * 16 + l16) * 72 + 32 + quad * 8);
      f32x4 a = (f32x4){0.f, 0.f, 0.f, 0.f};
      a = __builtin_amdgcn_mfma_f32_16x16x32_bf16(qS0, b0, a, 0, 0, 0);
      a = __builtin_amdgcn_mfma_f32_16x16x32_bf16(qS1, b1, a, 0, 0, 0);
      sS[nt] = a;
      f32x4 c = (f32x4){0.f, 0.f, 0.f, 0.f};
      c = __builtin_amdgcn_mfma_f32_16x16x32_bf16(qP0, b0, c, 0, 0, 0);
      c = __builtin_amdgcn_mfma_f32_16x16x32_bf16(qP1, b1, c, 0, 0, 0);
      sP[nt] = c;
    }
    float mb[4];
#pragma unroll
    for (int nt = 0; nt < 4; nt++) mb[nt] = mbias[nt * 16 + l16];
#pragma unroll
    for (int nt = 0; nt < 4; nt++)
#pragma unroll
      for (int i = 0; i < 4; i++) {
        sS[nt][i] = sS[nt][i] * 0.125f + mb[nt];
        sP[nt][i] = sP[nt][i] * 0.125f + mb[nt];
      }

    // ---- online softmax (both streams) ----
#pragma unroll
    for (int i = 0; i < 4; i++) {
      float m = fmaxf(fmaxf(sS[0][i], sS[1][i]), fmaxf(sS[2][i], sS[3][i]));
#pragma unroll
      for (int off = 1; off < 16; off <<= 1) m = fmaxf(m, __shfl_xor(m, off, 64));
      float mn = fmaxf(mS[i], m);
      float alpha = __expf(mS[i] - mn);
      mS[i] = mn;
#pragma unroll
      for (int d = 0; d < 4; d++) oS[d][i] *= alpha;
      lS[i] *= alpha;
    }
#pragma unroll
    for (int i = 0; i < 4; i++) {
      float m = fmaxf(fmaxf(sP[0][i], sP[1][i]), fmaxf(sP[2][i], sP[3][i]));
#pragma unroll
      for (int off = 1; off < 16; off <<= 1) m = fmaxf(m, __shfl_xor(m, off, 64));
      float mn = fmaxf(mP[i], m);
      float alpha = __expf(mP[i] - mn);
      mP[i] = mn;
#pragma unroll
      for (int d = 0; d < 4; d++) oP[d][i] *= alpha;
      lP[i] *= alpha;
    }
#pragma unroll
    for (int nt = 0; nt < 4; nt++)
#pragma unroll
      for (int i = 0; i < 4; i++) {
        pwS[(quad * 4 + i) * 72 + nt * 16 + l16] = f2bf(__expf(sS[nt][i] - mS[i]));
        pwP[(quad * 4 + i) * 72 + nt * 16 + l16] = f2bf(__expf(sP[nt][i] - mP[i]));
      }
    __syncthreads();  // P tiles visible

    // ---- O += P @ V, l += P @ ones (V fragments read ONCE) ----
#pragma unroll
    for (int ks = 0; ks < 2; ks++) {
      bf16x8 paS = *(const bf16x8*)(pwS + l16 * 72 + ks * 32 + quad * 8);
      bf16x8 paP = *(const bf16x8*)(pwP + l16 * 72 + ks * 32 + quad * 8);
      lS = __builtin_amdgcn_mfma_f32_16x16x32_bf16(paS, vbOnes, lS, 0, 0, 0);
      lP = __builtin_amdgcn_mfma_f32_16x16x32_bf16(paP, vbOnes, lP, 0, 0, 0);
#pragma unroll
      for (int d = 0; d < 4; d++) {
        bf16x8 vb = *(const bf16x8*)(Vt + (d * 16 + l16) * 64 +
                                     (((ks * 4 + quad) ^ (l16 & 7)) << 3));
        oS[d] = __builtin_amdgcn_mfma_f32_16x16x32_bf16(paS, vb, oS[d], 0, 0, 0);
        oP[d] = __builtin_amdgcn_mfma_f32_16x16x32_bf16(paP, vb, oP[d], 0, 0, 0);
      }
    }
  }

  // ---- epilogue: l lives in lane l16==0 of each quad group; broadcast ----
#pragma unroll
  for (int i = 0; i < 4; i++) {
    const float lsv = __shfl(lS[i], lane & 48, 64);
    const float lpv = __shfl(lP[i], lane & 48, 64);
    const float invS = 1.0f / lsv;
    const float invP = 1.0f / lpv;
    const int q = q0 + quad * 4 + i;
    const size_t ob = base + (size_t)q * 64;
#pragma unroll
    for (int d = 0; d < 4; d++) {
      OUTs[ob + d * 16 + l16] = f2bf(oS[d][i] * invS);
      OUTp[ob + d * 16 + l16] = f2bf(oP[d][i] * invP);
    }
  }
}

// =====================================================================
extern "C" void kernel_launch(void* const* d_in, const int* in_sizes, int n_in,
                              void* d_out, int out_size, void* d_ws, size_t ws_size,
                              hipStream_t stream) {
  const float* Qpoi = (const float*)d_in[0];
  const float* Qsvi = (const float*)d_in[1];
  const float* Kin  = (const float*)d_in[2];
  const float* Vin  = (const float*)d_in[3];
  const int* mask   = (const int*)d_in[4];
  const float* wq_poi_w = (const float*)d_in[5];
  const float* wq_poi_b = (const float*)d_in[6];
  const float* wq_svi_w = (const float*)d_in[7];
  const float* wq_svi_b = (const float*)d_in[8];
  const float* wk_w = (const float*)d_in[9];
  const float* wk_b = (const float*)d_in[10];
  const float* wv_w = (const float*)d_in[11];
  const float* wv_b = (const float*)d_in[12];
  const float* fc_w = (const float*)d_in[13];
  const float* fc_b = (const float*)d_in[14];

  const size_t SZ = (size_t)8 * 16 * 1024 * 64;   // 8,388,608 elems per slab
  const size_t WBE = (size_t)5 << 20;             // 5 weight matrices, bf16 elems
  u16* W0 = (u16*)d_ws;        // Kh head-layout -> later poi-ctx bounce
  u16* W1 = W0 + SZ;           // Vh TRANSPOSED head-layout -> later svi-ctx bounce
  u16* Wp = W1 + SZ;           // bf16 weights (5 x 1M elems) when ws fits
  const bool haveWb = ws_size >= (2 * SZ + WBE) * sizeof(u16);   // 44.0 MB

  float* Of = (float*)d_out;   // f32 [2][SZ]; poi half 0, svi half 1
  u16* R0 = (u16*)d_out;       // bf16 A slab 0
  u16* R1 = R0 + SZ;           // bf16 A slab 1
  u16* R2 = R0 + 2 * SZ;       // Qh_svi / ctx_svi
  u16* R3 = R0 + 3 * SZ;       // Qh_poi / ctx_poi

  dim3 bb(256, 1, 1);
  dim3 gg(8, 64, 2);   // batched gemm: 1024 blocks
  dim3 ga(16, 128);    // attn
  dim3 gc(4096, 1, 2); // batched conv pair

  // 1. weights -> bf16 (all 5 into ws); tier fallback: f32 weights in-GEMM
  if (haveWb) {
    W5 w5{{wk_w, wv_w, wq_svi_w, wq_poi_w, fc_w}};
    hipLaunchKernelGGL(conv_w_kernel, dim3(2560), bb, 0, stream, w5, Wp);
  }
  const u16* Wk  = Wp + ((size_t)0 << 20);
  const u16* Wv  = Wp + ((size_t)1 << 20);
  const u16* Wqs = Wp + ((size_t)2 << 20);
  const u16* Wqp = Wp + ((size_t)3 << 20);
  const u16* Wfc = Wp + ((size_t)4 << 20);

  // 2. phase A: K,V -> bf16; batched {K-proj->W0 (MODE0), V-proj->W1 (MODE2)}
  {
    C2 c{{Kin, Vin}, {R0, R1}};
    hipLaunchKernelGGL(conv2_kernel, gc, bb, 0, stream, c);
    GB g{{R0, R1},
         {haveWb ? (const void*)Wk : (const void*)wk_w, haveWb ? (const void*)Wv : (const void*)wv_w},
         {wk_b, wv_b}, {(void*)W0, (void*)W1}};
    if (haveWb) hipLaunchKernelGGL((gemm_bt<0, 2, 0, 1>), gg, bb, 0, stream, g);
    else        hipLaunchKernelGGL((gemm_bt<0, 2, 0, 0>), gg, bb, 0, stream, g);
  }

  // 3. phase B: Qsvi,Qpoi -> bf16; batched {svi-proj->R2, poi-proj->R3}
  {
    C2 c{{Qsvi, Qpoi}, {R0, R1}};
    hipLaunchKernelGGL(conv2_kernel, gc, bb, 0, stream, c);
    GB g{{R0, R1},
         {haveWb ? (const void*)Wqs : (const void*)wq_svi_w, haveWb ? (const void*)Wqp : (const void*)wq_poi_w},
         {wq_svi_b, wq_poi_b}, {(void*)R2, (void*)R3}};
    if (haveWb) hipLaunchKernelGGL((gemm_bt<0, 0, 0, 1>), gg, bb, 0, stream, g);
    else        hipLaunchKernelGGL((gemm_bt<0, 0, 0, 0>), gg, bb, 0, stream, g);
  }

  // 4. fused attention, ctx in-place (own-Q-rows trick)
  hipLaunchKernelGGL(attn2_kernel, ga, bb, 0, stream,
                     (const u16*)R2, (const u16*)R3, (const u16*)W0, (const u16*)W1,
                     mask, R2, R3);

  // 5. bounce ctx out of d_out (Kh/Vt dead after attn); then batched fc
  hipMemcpyAsync(W0, R3, SZ * sizeof(u16), hipMemcpyDeviceToDevice, stream);  // poi ctx
  hipMemcpyAsync(W1, R2, SZ * sizeof(u16), hipMemcpyDeviceToDevice, stream);  // svi ctx
  {
    GB g{{W0, W1},
         {haveWb ? (const void*)Wfc : (const void*)fc_w, haveWb ? (const void*)Wfc : (const void*)fc_w},
         {fc_b, fc_b}, {(void*)Of, (void*)(Of + SZ)}};
    if (haveWb) hipLaunchKernelGGL((gemm_bt<1, 1, 1, 1>), gg, bb, 0, stream, g);
    else        hipLaunchKernelGGL((gemm_bt<1, 1, 1, 0>), gg, bb, 0, stream, g);
  }
}

// Round 8
// 473.976 us; speedup vs baseline: 1.2073x; 1.2073x over previous
//
#include <hip/hip_runtime.h>

typedef unsigned short u16;
typedef unsigned int u32;
typedef short bf16x8 __attribute__((ext_vector_type(8)));
typedef float f32x4 __attribute__((ext_vector_type(4)));

// ---- bf16 helpers ----
__device__ __forceinline__ u16 f2bf(float f) {
  union { float f; u32 i; } v; v.f = f;
  u32 x = v.i;
  return (u16)((x + 0x7fffu + ((x >> 16) & 1u)) >> 16);  // RNE
}

// packed f32x2 -> bf16x2 (lo = a, hi = b), RNE (gfx950 instr; T12 recipe)
__device__ __forceinline__ u32 cvtpk_bf16(float a, float b) {
  u32 r;
  asm("v_cvt_pk_bf16_f32 %0, %1, %2" : "=v"(r) : "v"(a), "v"(b));
  return r;
}

union Pack16 { u16 h[16]; float4 f4[2]; };

// ---- direct global->LDS DMA, 16B per lane (wave-uniform LDS base) ----
__device__ __forceinline__ void gld16(const u16* g, u16* l) {
  __builtin_amdgcn_global_load_lds((const __attribute__((address_space(1))) u32*)g,
                                   (__attribute__((address_space(3))) u32*)l, 16, 0, 0);
}

// =====================================================================
// f32 -> bf16 streaming converters (z-batched pair + 5-weight batch)
// =====================================================================
struct C2 { const float* s[2]; u16* d[2]; };
__global__ __launch_bounds__(256) void conv2_kernel(C2 c) {
  const int z = blockIdx.z;
  const size_t i = (size_t)blockIdx.x * 256 + threadIdx.x;  // x8 elems
  const float4* s = (const float4*)c.s[z] + i * 2;
  float4 a = s[0], b = s[1];
  union { u16 h[8]; float4 f; } o;
  o.h[0] = f2bf(a.x); o.h[1] = f2bf(a.y); o.h[2] = f2bf(a.z); o.h[3] = f2bf(a.w);
  o.h[4] = f2bf(b.x); o.h[5] = f2bf(b.y); o.h[6] = f2bf(b.z); o.h[7] = f2bf(b.w);
  *(float4*)(c.d[z] + i * 8) = o.f;
}

struct W5 { const float* p[5]; };
__global__ __launch_bounds__(256) void conv_w_kernel(W5 w, u16* __restrict__ dst) {
  const int m = blockIdx.x >> 9;                                    // matrix idx
  const size_t i = (size_t)(blockIdx.x & 511) * 256 + threadIdx.x;  // x8 elems
  const float4* s = (const float4*)w.p[m] + i * 2;
  float4 a = s[0], b = s[1];
  union { u16 h[8]; float4 f; } o;
  o.h[0] = f2bf(a.x); o.h[1] = f2bf(a.y); o.h[2] = f2bf(a.z); o.h[3] = f2bf(a.w);
  o.h[4] = f2bf(b.x); o.h[5] = f2bf(b.y); o.h[6] = f2bf(b.z); o.h[7] = f2bf(b.w);
  *(float4*)(dst + ((size_t)m << 20) + i * 8) = o.f;
}

// ---- per-lane global address of a 16B chunk of the A operand ----
template<int ASRC>
__device__ __forceinline__ const u16* aAddr(const u16* A, int row, int k) {
  if constexpr (ASRC == 0) {
    return A + (size_t)row * 1024 + k;
  } else {
    const int n = row >> 10, s = row & 1023, h = k >> 6;
    return A + ((size_t)((n * 16 + h) * 1024 + s)) * 64 + (k & 63);
  }
}

// =====================================================================
// z-BATCHED GEMM, 2-PHASE DOUBLE-BUFFERED (unchanged from round 7 —
// confirmed ~+20%/clock vs single-buffer).
// =====================================================================
struct GB { const void* A[2]; const void* W[2]; const float* bias[2]; void* out[2]; };

template<int MODEA, int MODEB, int ASRC, int WBF>
__global__ __launch_bounds__(256, 2) void gemm_bt(GB gb) {
  __shared__ __align__(16) u16 At[2][128 * 32];
  __shared__ __align__(16) u16 Bt[2][128 * 32];

  const int z = blockIdx.z;
  const u16* Ab = (const u16*)gb.A[z];
  const u16* Wb = (const u16*)gb.W[z];
  const float* bias = gb.bias[z];
  void* outv = gb.out[z];
  const int mode = z ? MODEB : MODEA;

  const int tid = threadIdx.x;
  const int lane = tid & 63, wave = tid >> 6;
  const int quad = lane >> 4, l16 = lane & 15;
  const int bm = blockIdx.y * 128, bn = blockIdx.x * 128;
  const int wm = (wave >> 1) * 64, wn = (wave & 1) * 64;

  const int r0 = wave * 32;
  const int lk = (lane & 3) * 8;

  const int srow = tid >> 1, scol = (tid & 1) * 16;  // W f32 fallback coords

  f32x4 acc[4][4];
#pragma unroll
  for (int i = 0; i < 4; i++)
#pragma unroll
    for (int j = 0; j < 4; j++) acc[i][j] = (f32x4){0.f, 0.f, 0.f, 0.f};

  float4 wf[4];

  auto loadWf = [&](int k0) {
    const float* wp = (const float*)Wb + (size_t)(bn + srow) * 1024 + k0 + scol;
#pragma unroll
    for (int q = 0; q < 4; q++) wf[q] = ((const float4*)wp)[q];
  };
  auto stageA = [&](int b, int k0) {
    const int row = bm + r0 + (lane >> 2);
    gld16(aAddr<ASRC>(Ab, row, k0 + lk), At[b] + r0 * 32);
    gld16(aAddr<ASRC>(Ab, row + 16, k0 + lk), At[b] + (r0 + 16) * 32);
  };
  auto stageW = [&](int b, int k0) {
    if constexpr (WBF) {
      const int row = bn + r0 + (lane >> 2);
      gld16(Wb + (size_t)row * 1024 + k0 + lk, Bt[b] + r0 * 32);
      gld16(Wb + (size_t)(row + 16) * 1024 + k0 + lk, Bt[b] + (r0 + 16) * 32);
    } else {
      Pack16 pb;
#pragma unroll
      for (int q = 0; q < 4; q++) {
        pb.h[q * 4 + 0] = f2bf(wf[q].x);
        pb.h[q * 4 + 1] = f2bf(wf[q].y);
        pb.h[q * 4 + 2] = f2bf(wf[q].z);
        pb.h[q * 4 + 3] = f2bf(wf[q].w);
      }
      *(float4*)(Bt[b] + srow * 32 + scol) = pb.f4[0];
      *(float4*)(Bt[b] + srow * 32 + scol + 8) = pb.f4[1];
    }
  };

  if constexpr (!WBF) loadWf(0);
  stageA(0, 0);
  stageW(0, 0);
  if constexpr (!WBF) loadWf(32);

  for (int t = 0; t < 32; ++t) {
    const int cb = t & 1, nb = cb ^ 1;
    __syncthreads();  // drains loads issued one full iteration ago
    if (t + 1 < 32) {
      stageA(nb, (t + 1) * 32);
      stageW(nb, (t + 1) * 32);
      if constexpr (!WBF) if (t + 2 < 32) loadWf((t + 2) * 32);
    }

    bf16x8 af[4], bfr[4];
#pragma unroll
    for (int mt = 0; mt < 4; mt++)
      af[mt] = *(const bf16x8*)(At[cb] + (wm + mt * 16 + l16) * 32 + quad * 8);
#pragma unroll
    for (int nt = 0; nt < 4; nt++)
      bfr[nt] = *(const bf16x8*)(Bt[cb] + (wn + nt * 16 + l16) * 32 + quad * 8);
#pragma unroll
    for (int mt = 0; mt < 4; mt++)
#pragma unroll
      for (int nt = 0; nt < 4; nt++)
        acc[mt][nt] = __builtin_amdgcn_mfma_f32_16x16x32_bf16(af[mt], bfr[nt], acc[mt][nt], 0, 0, 0);
  }

#pragma unroll
  for (int mt = 0; mt < 4; mt++) {
#pragma unroll
    for (int nt = 0; nt < 4; nt++) {
      const int col = bn + wn + nt * 16 + l16;
      const float bv = bias[col];
#pragma unroll
      for (int i = 0; i < 4; i++) {
        const int row = bm + wm + mt * 16 + quad * 4 + i;
        const float v = acc[mt][nt][i] + bv;
        if (mode == 0) {
          const int s = row >> 3, n = row & 7;
          const int h = col >> 6, dk = col & 63;
          ((u16*)outv)[(size_t)(((n * 16 + h) * 1024 + s) * 64 + dk)] = f2bf(v);
        } else if (mode == 1) {
          const int n = row >> 10, s = row & 1023;
          ((float*)outv)[(size_t)((s * 8 + n) * 1024 + col)] = v;
        } else {
          const int s = row >> 3, n = row & 7;
          const int h = col >> 6, dk = col & 63;
          ((u16*)outv)[(size_t)(((n * 16 + h) * 64 + dk) * 1024 + s)] = f2bf(v);
        }
      }
    }
  }
}

// =====================================================================
// FUSED dual-stream flash attention, SWAPPED QK^T (T12 family):
// S = mfma(K,Q) -> S[key][q] with q = lane column; softmax row-reduce
// is 2 shfl_xor (was 16); P packed via v_cvt_pk_bf16_f32 into 4
// ds_write_b64/stream (was 16 b16) into XOR-swizzled [q][k] tile; PV
// A-fragment = 1 ds_read_b128 (unchanged pattern). Defer-max (T13,
// THR=8), l via f32 sums, P is wave-private -> no 3rd barrier.
// =====================================================================
__global__ __launch_bounds__(256, 2) void attn2_kernel(const u16* __restrict__ Qs_g,
                                                       const u16* __restrict__ Qp_g,
                                                       const u16* __restrict__ K,
                                                       const u16* __restrict__ Vt_g,
                                                       const int* __restrict__ mask,
                                                       u16* __restrict__ OUTs,
                                                       u16* __restrict__ OUTp) {
  __shared__ __align__(16) u16 Ks[64 * 72];      // [key][dk], stride 72
  __shared__ __align__(16) u16 Vt[64 * 64];      // [dk][key], XOR-swizzled 8-key blocks
  __shared__ __align__(16) u16 Ps[4][2][1024];   // [wave][stream][q=16][k=64] swizzled
  __shared__ float mbias[64];

  const int tid = threadIdx.x;
  const int lane = tid & 63, wave = tid >> 6;
  const int quad = lane >> 4, l16 = lane & 15;
  const int qt = blockIdx.x, nh = blockIdx.y;
  const int n = nh >> 4;
  const size_t base = (size_t)nh << 16;  // nh * 1024*64

  const int q0 = qt * 64 + wave * 16;
  bf16x8 qS0, qS1, qP0, qP1;  // Q fragments; used as B-operand (col=q=l16, regs=dk)
  {
    const u16* qp = Qs_g + base + (size_t)(q0 + l16) * 64 + quad * 8;
    qS0 = *(const bf16x8*)qp;
    qS1 = *(const bf16x8*)(qp + 32);
    const u16* qq = Qp_g + base + (size_t)(q0 + l16) * 64 + quad * 8;
    qP0 = *(const bf16x8*)qq;
    qP1 = *(const bf16x8*)(qq + 32);
  }

  float mS = -1e30f, mP = -1e30f, lS = 0.f, lP = 0.f;  // per-lane: query q=l16
  f32x4 oS[4], oP[4];  // O[q=quad*4+i][d=d*16+l16] (unchanged layout)
#pragma unroll
  for (int d = 0; d < 4; d++) { oS[d] = (f32x4){0.f, 0.f, 0.f, 0.f}; oP[d] = (f32x4){0.f, 0.f, 0.f, 0.f}; }

  const int sr = tid >> 2;
  const int sc = (tid & 3) * 16;
  const u16* kbase = K + base + (size_t)sr * 64 + sc;
  const u16* vbase = Vt_g + base + (size_t)sr * 1024 + sc;
  u16* vdst0 = Vt + sr * 64 + ((((sc >> 3) + 0) ^ (sr & 7)) << 3);
  u16* vdst1 = Vt + sr * 64 + ((((sc >> 3) + 1) ^ (sr & 7)) << 3);
  u16* psS = &Ps[wave][0][0];
  u16* psP = &Ps[wave][1][0];

  // ---- prologue: prefetch tile 0 into regs ----
  float4 kv0 = *(const float4*)(kbase);
  float4 kv1 = *(const float4*)(kbase + 8);
  float4 vv0 = *(const float4*)(vbase);
  float4 vv1 = *(const float4*)(vbase + 8);
  int mk = (tid < 64) ? mask[n * 1024 + tid] : 0;

  for (int kt = 0; kt < 16; kt++) {
    __syncthreads();  // previous iteration's Ks/Vt reads complete
    *(float4*)(Ks + sr * 72 + sc) = kv0;
    *(float4*)(Ks + sr * 72 + sc + 8) = kv1;
    *(float4*)vdst0 = vv0;
    *(float4*)vdst1 = vv1;
    if (tid < 64) mbias[tid] = mk ? -1e30f : 0.0f;
    __syncthreads();

    if (kt + 1 < 16) {  // prefetch next tile (hides under compute)
      kv0 = *(const float4*)(kbase + (kt + 1) * 64 * 64);
      kv1 = *(const float4*)(kbase + (kt + 1) * 64 * 64 + 8);
      vv0 = *(const float4*)(vbase + (kt + 1) * 64);
      vv1 = *(const float4*)(vbase + (kt + 1) * 64 + 8);
      mk = (tid < 64) ? mask[n * 1024 + (kt + 1) * 64 + tid] : 0;
    }

    // ---- S = K Q (swapped): sX[nt][i] = S[key=nt*16+quad*4+i][q=l16] ----
    f32x4 sS[4], sP[4];
#pragma unroll
    for (int nt = 0; nt < 4; nt++) {
      bf16x8 b0 = *(const bf16x8*)(Ks + (nt * 16 + l16) * 72 + quad * 8);
      bf16x8 b1 = *(const bf16x8*)(Ks + (nt * 16 + l16) * 72 + 32 + quad * 8);
      f32x4 a = (f32x4){0.f, 0.f, 0.f, 0.f};
      a = __builtin_amdgcn_mfma_f32_16x16x32_bf16(b0, qS0, a, 0, 0, 0);
      a = __builtin_amdgcn_mfma_f32_16x16x32_bf16(b1, qS1, a, 0, 0, 0);
      sS[nt] = a;
      f32x4 c = (f32x4){0.f, 0.f, 0.f, 0.f};
      c = __builtin_amdgcn_mfma_f32_16x16x32_bf16(b0, qP0, c, 0, 0, 0);
      c = __builtin_amdgcn_mfma_f32_16x16x32_bf16(b1, qP1, c, 0, 0, 0);
      sP[nt] = c;
    }
    // scale + per-KEY mask bias (key = row now; quad-uniform LDS broadcast)
#pragma unroll
    for (int nt = 0; nt < 4; nt++)
#pragma unroll
      for (int i = 0; i < 4; i++) {
        const float mb = mbias[nt * 16 + quad * 4 + i];
        sS[nt][i] = sS[nt][i] * 0.125f + mb;
        sP[nt][i] = sP[nt][i] * 0.125f + mb;
      }

    // ---- per-query max: 16 local + 2 cross-quad shfl ----
    float mlS = sS[0][0], mlP = sP[0][0];
#pragma unroll
    for (int nt = 0; nt < 4; nt++)
#pragma unroll
      for (int i = 0; i < 4; i++) {
        if (nt || i) { mlS = fmaxf(mlS, sS[nt][i]); mlP = fmaxf(mlP, sP[nt][i]); }
      }
    mlS = fmaxf(mlS, __shfl_xor(mlS, 16, 64));
    mlS = fmaxf(mlS, __shfl_xor(mlS, 32, 64));
    mlP = fmaxf(mlP, __shfl_xor(mlP, 16, 64));
    mlP = fmaxf(mlP, __shfl_xor(mlP, 32, 64));

    // ---- defer-max (T13): rescale only when max grew by > 8 ----
    if (!__all(mlS - mS <= 8.0f)) {
      const float mn = fmaxf(mS, mlS);
      const float al = __expf(mS - mn);
      mS = mn; lS *= al;
      float a0 = __shfl(al, quad * 4 + 0, 64), a1 = __shfl(al, quad * 4 + 1, 64);
      float a2 = __shfl(al, quad * 4 + 2, 64), a3 = __shfl(al, quad * 4 + 3, 64);
#pragma unroll
      for (int d = 0; d < 4; d++) { oS[d][0] *= a0; oS[d][1] *= a1; oS[d][2] *= a2; oS[d][3] *= a3; }
    }
    if (!__all(mlP - mP <= 8.0f)) {
      const float mn = fmaxf(mP, mlP);
      const float al = __expf(mP - mn);
      mP = mn; lP *= al;
      float a0 = __shfl(al, quad * 4 + 0, 64), a1 = __shfl(al, quad * 4 + 1, 64);
      float a2 = __shfl(al, quad * 4 + 2, 64), a3 = __shfl(al, quad * 4 + 3, 64);
#pragma unroll
      for (int d = 0; d < 4; d++) { oP[d][0] *= a0; oP[d][1] *= a1; oP[d][2] *= a2; oP[d][3] *= a3; }
    }

    // ---- exp, l-sum, cvt_pk pack, swizzled b64 P-write (wave-private) ----
    // write offset (u16): q(l16)*64 + ((2nt+(quad>>1)) ^ (l16&7))*8 + (quad&1)*4
    float lsS = 0.f, lsP = 0.f;
#pragma unroll
    for (int nt = 0; nt < 4; nt++) {
      const int woff = l16 * 64 + (((2 * nt + (quad >> 1)) ^ (l16 & 7)) << 3) + ((quad & 1) << 2);
      float p0 = __expf(sS[nt][0] - mS), p1 = __expf(sS[nt][1] - mS);
      float p2 = __expf(sS[nt][2] - mS), p3 = __expf(sS[nt][3] - mS);
      lsS += (p0 + p1) + (p2 + p3);
      uint2 w; w.x = cvtpk_bf16(p0, p1); w.y = cvtpk_bf16(p2, p3);
      *(uint2*)(psS + woff) = w;
      p0 = __expf(sP[nt][0] - mP); p1 = __expf(sP[nt][1] - mP);
      p2 = __expf(sP[nt][2] - mP); p3 = __expf(sP[nt][3] - mP);
      lsP += (p0 + p1) + (p2 + p3);
      uint2 u; u.x = cvtpk_bf16(p0, p1); u.y = cvtpk_bf16(p2, p3);
      *(uint2*)(psP + woff) = u;
    }
    lsS += __shfl_xor(lsS, 16, 64); lsS += __shfl_xor(lsS, 32, 64);
    lsP += __shfl_xor(lsP, 16, 64); lsP += __shfl_xor(lsP, 32, 64);
    lS += lsS;
    lP += lsP;

    // ---- O += P @ V (no barrier: P is wave-private, DS in-order) ----
#pragma unroll
    for (int ks = 0; ks < 2; ks++) {
      const int roff = l16 * 64 + ((((ks * 4 + quad) ^ (l16 & 7))) << 3);
      bf16x8 paS = *(const bf16x8*)(psS + roff);
      bf16x8 paP = *(const bf16x8*)(psP + roff);
#pragma unroll
      for (int d = 0; d < 4; d++) {
        bf16x8 vb = *(const bf16x8*)(Vt + (d * 16 + l16) * 64 +
                                     (((ks * 4 + quad) ^ (l16 & 7)) << 3));
        oS[d] = __builtin_amdgcn_mfma_f32_16x16x32_bf16(paS, vb, oS[d], 0, 0, 0);
        oP[d] = __builtin_amdgcn_mfma_f32_16x16x32_bf16(paP, vb, oP[d], 0, 0, 0);
      }
    }
  }

  // ---- epilogue: l lives per-lane at q=l16; redistribute to q=quad*4+i ----
  float liS[4], liP[4];
#pragma unroll
  for (int i = 0; i < 4; i++) {
    liS[i] = __shfl(lS, quad * 4 + i, 64);
    liP[i] = __shfl(lP, quad * 4 + i, 64);
  }
#pragma unroll
  for (int i = 0; i < 4; i++) {
    const float invS = 1.0f / liS[i];
    const float invP = 1.0f / liP[i];
    const int q = q0 + quad * 4 + i;
    const size_t ob = base + (size_t)q * 64;
#pragma unroll
    for (int d = 0; d < 4; d++) {
      OUTs[ob + d * 16 + l16] = f2bf(oS[d][i] * invS);
      OUTp[ob + d * 16 + l16] = f2bf(oP[d][i] * invP);
    }
  }
}

// =====================================================================
extern "C" void kernel_launch(void* const* d_in, const int* in_sizes, int n_in,
                              void* d_out, int out_size, void* d_ws, size_t ws_size,
                              hipStream_t stream) {
  const float* Qpoi = (const float*)d_in[0];
  const float* Qsvi = (const float*)d_in[1];
  const float* Kin  = (const float*)d_in[2];
  const float* Vin  = (const float*)d_in[3];
  const int* mask   = (const int*)d_in[4];
  const float* wq_poi_w = (const float*)d_in[5];
  const float* wq_poi_b = (const float*)d_in[6];
  const float* wq_svi_w = (const float*)d_in[7];
  const float* wq_svi_b = (const float*)d_in[8];
  const float* wk_w = (const float*)d_in[9];
  const float* wk_b = (const float*)d_in[10];
  const float* wv_w = (const float*)d_in[11];
  const float* wv_b = (const float*)d_in[12];
  const float* fc_w = (const float*)d_in[13];
  const float* fc_b = (const float*)d_in[14];

  const size_t SZ = (size_t)8 * 16 * 1024 * 64;   // 8,388,608 elems per slab
  const size_t WBE = (size_t)5 << 20;             // 5 bf16 weight matrices (elems)
  u16* W0 = (u16*)d_ws;        // Kh head-layout (poi-ctx bounce if needed)
  u16* W1 = W0 + SZ;           // Vh^T head-layout (svi-ctx bounce if needed)
  u16* Wp = W1 + SZ;           // bf16 weights
  u16* W2 = Wp + WBE;          // svi-ctx (tier)
  u16* W3 = W2 + SZ;           // poi-ctx (tier)
  const bool haveWb = ws_size >= (2 * SZ + WBE) * sizeof(u16);
  const bool haveW2 = ws_size >= (3 * SZ + WBE) * sizeof(u16);
  const bool haveW3 = ws_size >= (4 * SZ + WBE) * sizeof(u16);

  float* Of = (float*)d_out;   // f32 [2][SZ]; poi half 0, svi half 1
  u16* R0 = (u16*)d_out;       // bf16 A slab 0
  u16* R1 = R0 + SZ;           // bf16 A slab 1
  u16* R2 = R0 + 2 * SZ;       // Qh_svi / ctx_svi (fallback)
  u16* R3 = R0 + 3 * SZ;       // Qh_poi / ctx_poi (fallback)

  dim3 bb(256, 1, 1);
  dim3 gg(8, 64, 2);   // batched gemm: 1024 blocks
  dim3 ga(16, 128);    // attn
  dim3 gc(4096, 1, 2); // batched conv pair

  // 1. weights -> bf16
  if (haveWb) {
    W5 w5{{wk_w, wv_w, wq_svi_w, wq_poi_w, fc_w}};
    hipLaunchKernelGGL(conv_w_kernel, dim3(2560), bb, 0, stream, w5, Wp);
  }
  const u16* Wk  = Wp + ((size_t)0 << 20);
  const u16* Wv  = Wp + ((size_t)1 << 20);
  const u16* Wqs = Wp + ((size_t)2 << 20);
  const u16* Wqp = Wp + ((size_t)3 << 20);
  const u16* Wfc = Wp + ((size_t)4 << 20);

  // 2. phase A: K,V -> bf16; batched {K-proj->W0 (MODE0), V-proj->W1 (MODE2)}
  {
    C2 c{{Kin, Vin}, {R0, R1}};
    hipLaunchKernelGGL(conv2_kernel, gc, bb, 0, stream, c);
    GB g{{R0, R1},
         {haveWb ? (const void*)Wk : (const void*)wk_w, haveWb ? (const void*)Wv : (const void*)wv_w},
         {wk_b, wv_b}, {(void*)W0, (void*)W1}};
    if (haveWb) hipLaunchKernelGGL((gemm_bt<0, 2, 0, 1>), gg, bb, 0, stream, g);
    else        hipLaunchKernelGGL((gemm_bt<0, 2, 0, 0>), gg, bb, 0, stream, g);
  }

  // 3. phase B: Qsvi,Qpoi -> bf16; batched {svi-proj->R2, poi-proj->R3}
  {
    C2 c{{Qsvi, Qpoi}, {R0, R1}};
    hipLaunchKernelGGL(conv2_kernel, gc, bb, 0, stream, c);
    GB g{{R0, R1},
         {haveWb ? (const void*)Wqs : (const void*)wq_svi_w, haveWb ? (const void*)Wqp : (const void*)wq_poi_w},
         {wq_svi_b, wq_poi_b}, {(void*)R2, (void*)R3}};
    if (haveWb) hipLaunchKernelGGL((gemm_bt<0, 0, 0, 1>), gg, bb, 0, stream, g);
    else        hipLaunchKernelGGL((gemm_bt<0, 0, 0, 0>), gg, bb, 0, stream, g);
  }

  // 4. fused attention; ctx to ws tiers when available (else in-place)
  u16* ctxS = (haveWb && haveW2) ? W2 : R2;
  u16* ctxP = (haveWb && haveW3) ? W3 : R3;
  hipLaunchKernelGGL(attn2_kernel, ga, bb, 0, stream,
                     (const u16*)R2, (const u16*)R3, (const u16*)W0, (const u16*)W1,
                     mask, ctxS, ctxP);

  // 5. fc inputs must live outside d_out (fc writes f32 over all 4 slabs)
  const u16* Ap;
  const u16* As;
  if (haveWb && haveW3) { Ap = W3; }
  else { hipMemcpyAsync(W0, ctxP, SZ * sizeof(u16), hipMemcpyDeviceToDevice, stream); Ap = W0; }
  if (haveWb && haveW2) { As = W2; }
  else { hipMemcpyAsync(W1, ctxS, SZ * sizeof(u16), hipMemcpyDeviceToDevice, stream); As = W1; }
  {
    GB g{{Ap, As},
         {haveWb ? (const void*)Wfc : (const void*)fc_w, haveWb ? (const void*)Wfc : (const void*)fc_w},
         {fc_b, fc_b}, {(void*)Of, (void*)(Of + SZ)}};
    if (haveWb) hipLaunchKernelGGL((gemm_bt<1, 1, 1, 1>), gg, bb, 0, stream, g);
    else        hipLaunchKernelGGL((gemm_bt<1, 1, 1, 0>), gg, bb, 0, stream, g);
  }
}